// Round 1
// 336.108 us; speedup vs baseline: 1.0505x; 1.0505x over previous
//
#include <hip/hip_runtime.h>
#include <hip/hip_bf16.h>

typedef __attribute__((ext_vector_type(4))) float floatx4;
typedef __attribute__((ext_vector_type(8))) short shortx8;

struct bf4 { __hip_bfloat16 h[4]; };
union U8 { shortx8 v; __hip_bfloat16 h[8]; };
union U4 { unsigned long long v; __hip_bfloat16 h[4]; };

__device__ __forceinline__ void async_copy16(const __hip_bfloat16* g, __hip_bfloat16* l) {
  __builtin_amdgcn_global_load_lds((__attribute__((address_space(1))) void*)g,
                                   (__attribute__((address_space(3))) void*)l,
                                   16, 0, 0);
}

// ---------------------------------------------------------------------------
// One-launch fp32 -> bf16 cast over 5 ranges (x, Wqkv, Wo, W1, W2).
// ---------------------------------------------------------------------------
__global__ __launch_bounds__(256) void cast_all_kernel(
    const float* __restrict__ s0, __hip_bfloat16* __restrict__ d0, int nb0,
    const float* __restrict__ s1, __hip_bfloat16* __restrict__ d1, int nb1,
    const float* __restrict__ s2, __hip_bfloat16* __restrict__ d2, int nb2,
    const float* __restrict__ s3, __hip_bfloat16* __restrict__ d3, int nb3,
    const float* __restrict__ s4, __hip_bfloat16* __restrict__ d4) {
  int b = blockIdx.x;
  const float* src; __hip_bfloat16* dst;
  if (b < nb0) { src = s0; dst = d0; }
  else { b -= nb0;
    if (b < nb1) { src = s1; dst = d1; }
    else { b -= nb1;
      if (b < nb2) { src = s2; dst = d2; }
      else { b -= nb2;
        if (b < nb3) { src = s3; dst = d3; }
        else { b -= nb3; src = s4; dst = d4; }
      }
    }
  }
  const int i = b * 256 + threadIdx.x;
  const float4 v = ((const float4*)src)[i];
  bf4 o4;
  o4.h[0] = __float2bfloat16(v.x);
  o4.h[1] = __float2bfloat16(v.y);
  o4.h[2] = __float2bfloat16(v.z);
  o4.h[3] = __float2bfloat16(v.w);
  *(bf4*)(dst + (size_t)i * 4) = o4;
}

// ===========================================================================
// Round 8: 256x256 8-phase GEMM (T2 swizzle + T3/T4 counted vmcnt + T5).
// BK=64 split into two k-halves of 32; LDS ring of 4 k-half slots per
// operand ([256][32] bf16 = 16KB each; 128 KiB total). Phase = (ks, mh):
//   p0 (ks0,mh0): read B[ks0] frags + A[mh0], stage A(T+1,ks1)
//   p1 (ks0,mh1): read A[mh1],              stage B(T+1,ks1), vmcnt(8)
//   p2 (ks1,mh0): read B[ks1] frags + A[mh0], stage A(T+2,ks0)
//   p3 (ks1,mh1): read A[mh1],              stage B(T+2,ks0), vmcnt(8)
// Slot for (kt,ks) = (2*kt+ks)&3. Stage->consume distance 4-6 phases; the
// slot written at p2/p3 was last read at p0/p1 of the SAME tile, whose
// ds_reads are drained (lgkmcnt(0)) before p1's trailing barrier -> race-free.
// LDS swizzle: phys 16B-chunk = fq ^ ((row>>1)&3): the 16-lane column-slice
// read (rows R..R+15, fixed chunk) covers all 8 slots of a 128B bank cycle
// (2 lanes/slot = free). Both-sides: staging pre-swizzles the global source.
// ===========================================================================
#define STG_A(slot, kt, ks)                                                    \
  async_copy16(Ag + (size_t)(kt) * 64 + (size_t)(ks) * 32,                     \
               &As[slot][tid * 8]);                                            \
  async_copy16(Ag + (size_t)128 * K + (size_t)(kt) * 64 + (size_t)(ks) * 32,   \
               &As[slot][4096 + tid * 8]);

#define STG_B(slot, kt, ks)                                                    \
  async_copy16(Bg + (size_t)(kt) * 64 + (size_t)(ks) * 32,                     \
               &Bs[slot][tid * 8]);                                            \
  async_copy16(Bg + (size_t)128 * K + (size_t)(kt) * 64 + (size_t)(ks) * 32,   \
               &Bs[slot][4096 + tid * 8]);

#define G256_PHASE(SLOT, MH, BLOAD, STAGE_CODE, WAIT_CODE)                     \
  {                                                                            \
    const __hip_bfloat16* Asl = As[SLOT];                                      \
    const __hip_bfloat16* Bsl = Bs[SLOT];                                      \
    if (BLOAD) {                                                               \
      _Pragma("unroll")                                                        \
      for (int ni = 0; ni < 4; ++ni)                                           \
        bfr[ni] = *(const shortx8*)&Bsl[brd + ni * 512];                       \
    }                                                                          \
    shortx8 afr[4];                                                            \
    _Pragma("unroll")                                                          \
    for (int mi4 = 0; mi4 < 4; ++mi4)                                          \
      afr[mi4] = *(const shortx8*)&Asl[ard + ((MH) * 4 + mi4) * 512];          \
    STAGE_CODE;                                                                \
    WAIT_CODE;                                                                 \
    __builtin_amdgcn_s_barrier();                                              \
    asm volatile("s_waitcnt lgkmcnt(0)" ::: "memory");                         \
    __builtin_amdgcn_sched_barrier(0);                                         \
    __builtin_amdgcn_s_setprio(1);                                             \
    _Pragma("unroll")                                                          \
    for (int mi4 = 0; mi4 < 4; ++mi4)                                          \
      _Pragma("unroll")                                                        \
      for (int ni = 0; ni < 4; ++ni)                                           \
        acc[(MH) * 4 + mi4][ni] = __builtin_amdgcn_mfma_f32_16x16x32_bf16(     \
            afr[mi4], bfr[ni], acc[(MH) * 4 + mi4][ni], 0, 0, 0);              \
    __builtin_amdgcn_s_setprio(0);                                             \
    __builtin_amdgcn_s_barrier();                                              \
  }

// C[M,N] = A[M,K] * B[N,K]^T, bf16 in, fp32 acc, 256x256 tile, 512 threads.
// EPI: 0 = +bias -> bf16; 1 = +bias, gelu -> bf16
template<int EPI>
__global__ __launch_bounds__(512, 2) void gemm256(
    const __hip_bfloat16* __restrict__ A,   // [M,K]
    const __hip_bfloat16* __restrict__ B,   // [N,K]
    const float* __restrict__ bias,         // [N]
    __hip_bfloat16* __restrict__ outb,
    int M, int N, int K, int NT)
{
  __shared__ __align__(16) __hip_bfloat16 As[4][256 * 32];
  __shared__ __align__(16) __hip_bfloat16 Bs[4][256 * 32];
  const int tid  = threadIdx.x;
  const int lane = tid & 63;
  const int wave = tid >> 6;        // 0..7
  const int wr = wave >> 2;         // 0..1 (M half, 128 rows)
  const int wc = wave & 3;          // 0..3 (N quarter, 64 cols)
  const int fr = lane & 15;
  const int fq = lane >> 4;         // 0..3

  // bijective XCD swizzle (nwg % 8 == 0 for both call sites)
  const int nwg = gridDim.x;
  const int cpx = nwg >> 3;
  const int swz = (blockIdx.x & 7) * cpx + (blockIdx.x >> 3);
  const int mt = swz / NT, nt = swz % NT;
  const long bm = (long)mt * 256, bn = (long)nt * 256;

  // staging: thread t covers linear LDS 16B-chunk (i*512+t) of a k-half slot;
  // row = i*128 + (t>>2), phys chunk = t&3 -> logical chunk pre-swizzled.
  const int srow = tid >> 2;                       // 0..127
  const int sch  = (tid & 3) ^ ((tid >> 3) & 3);   // source k-chunk (involution)
  const __hip_bfloat16* Ag = A + (bm + srow) * (size_t)K + sch * 8;
  const __hip_bfloat16* Bg = B + (bn + srow) * (size_t)K + sch * 8;

  // ds_read bases (elements), swizzled chunk = fq ^ ((row>>1)&3) = fq ^ ((fr>>1)&3)
  const int swc = (fq ^ ((fr >> 1) & 3)) << 3;
  const int ard = (wr * 128 + fr) * 32 + swc;
  const int brd = (wc * 64 + fr) * 32 + swc;

  const floatx4 zero = {0.f, 0.f, 0.f, 0.f};
  floatx4 acc[8][4];
#pragma unroll
  for (int mi = 0; mi < 8; ++mi)
#pragma unroll
    for (int ni = 0; ni < 4; ++ni) acc[mi][ni] = zero;

  const int NKT = K >> 6;           // K-tiles of 64 (>=2 at all call sites)

  // prologue: stage (0,ks0), (0,ks1), (1,ks0); wait the oldest k-half pair
  STG_A(0, 0, 0) STG_B(0, 0, 0)
  STG_A(1, 0, 1) STG_B(1, 0, 1)
  STG_A(2, 1, 0) STG_B(2, 1, 0)
  asm volatile("s_waitcnt vmcnt(8)" ::: "memory");
  __builtin_amdgcn_s_barrier();

  shortx8 bfr[4];
  for (int T = 0; T < NKT; ++T) {
    const int s00 = (2 * T) & 3;
    const int s01 = (2 * T + 1) & 3;
    const int sn1 = (2 * T + 3) & 3;   // (T+1, ks1)
    const int sn0 = (2 * T + 4) & 3;   // (T+2, ks0)
    const bool st1 = (T + 1 < NKT);
    const bool st2 = (T + 2 < NKT);

    G256_PHASE(s00, 0, true,
               { if (st1) { STG_A(sn1, T + 1, 1) } },
               {})
    G256_PHASE(s00, 1, false,
               { if (st1) { STG_B(sn1, T + 1, 1) } },
               { if (st1) { asm volatile("s_waitcnt vmcnt(8)" ::: "memory"); }
                 else     { asm volatile("s_waitcnt vmcnt(0)" ::: "memory"); } })
    G256_PHASE(s01, 0, true,
               { if (st2) { STG_A(sn0, T + 2, 0) } },
               {})
    G256_PHASE(s01, 1, false,
               { if (st2) { STG_B(sn0, T + 2, 0) } },
               { if (st2)      { asm volatile("s_waitcnt vmcnt(8)" ::: "memory"); }
                 else if (st1) { asm volatile("s_waitcnt vmcnt(4)" ::: "memory"); } })
  }

  // epilogue: C/D layout col = lane&15, row = (lane>>4)*4 + reg
#pragma unroll
  for (int mi = 0; mi < 8; ++mi) {
#pragma unroll
    for (int ni = 0; ni < 4; ++ni) {
      const long col = bn + wc * 64 + ni * 16 + fr;
      const float bv = bias[col];
#pragma unroll
      for (int r = 0; r < 4; ++r) {
        const long row = bm + wr * 128 + mi * 16 + fq * 4 + r;
        float v = acc[mi][ni][r] + bv;
        if (EPI == 1) {
          const float u = v + 0.044715f * v * v * v;
          v = v / (1.0f + __expf(-1.5957691216057308f * u));
        }
        outb[(size_t)row * N + col] = __float2bfloat16(v);
      }
    }
  }
}

// ---------------------------------------------------------------------------
// 128x128 split-K GEMM (round 7 structure) -> bf16 partials.
// ---------------------------------------------------------------------------
#define GEMM_SWIZZLE()                                                        \
  const int flat = blockIdx.x + gridDim.x * (blockIdx.y + 32 * blockIdx.z);   \
  const int xcd_ = flat & 7;                                                  \
  int rsw_ = flat >> 3;                                                       \
  const int mt_ = xcd_ * 4 + (rsw_ & 3);                                      \
  rsw_ >>= 2;                                                                 \
  const int nt_ = rsw_ % gridDim.x;                                           \
  const int zt_ = rsw_ / gridDim.x;

#define GEMM_STAGE(buf, koff)                                      \
  async_copy16(Ag0 + (koff),           &Asl[buf][tid * 8]);        \
  async_copy16(Ag0 + (koff) + rstride, &Asl[buf][tid * 8 + 2048]); \
  async_copy16(Bg0 + (koff),           &Bsl[buf][tid * 8]);        \
  async_copy16(Bg0 + (koff) + rstride, &Bsl[buf][tid * 8 + 2048]);

#define GEMM_KLOOP(NI)                                                        \
  GEMM_STAGE(0, 0)                                                            \
  GEMM_STAGE(1, 32)                                                           \
  int cur = 0;                                                                \
  for (int it = 0; it < (NI); ++it) {                                         \
    if (it + 2 < (NI)) {                                                      \
      const int nb = (cur >= 1) ? cur - 1 : cur + 2;  /* (cur+2)%3 */         \
      GEMM_STAGE(nb, (it + 2) * 32)                                           \
      asm volatile("s_waitcnt vmcnt(8)" ::: "memory");                        \
    } else if (it + 1 < (NI)) {                                               \
      asm volatile("s_waitcnt vmcnt(4)" ::: "memory");                        \
    } else {                                                                  \
      asm volatile("s_waitcnt vmcnt(0)" ::: "memory");                        \
    }                                                                         \
    asm volatile("s_barrier" ::: "memory");                                   \
    const __hip_bfloat16* Ac = Asl[cur];                                      \
    const __hip_bfloat16* Bc = Bsl[cur];                                      \
    shortx8 afr[4], bfr[4];                                                   \
    _Pragma("unroll")                                                         \
    for (int i = 0; i < 4; ++i) {                                             \
      afr[i] = *(const shortx8*)&Ac[(wr * 64 + i * 16 + fr) * 32 + sw];       \
      bfr[i] = *(const shortx8*)&Bc[(wc * 64 + i * 16 + fr) * 32 + sw];       \
    }                                                                         \
    _Pragma("unroll")                                                         \
    for (int mi = 0; mi < 4; ++mi)                                            \
      _Pragma("unroll")                                                       \
      for (int ni = 0; ni < 4; ++ni)                                          \
        acc[mi][ni] = __builtin_amdgcn_mfma_f32_16x16x32_bf16(                \
            afr[mi], bfr[ni], acc[mi][ni], 0, 0, 0);                          \
    asm volatile("s_barrier" ::: "memory");                                   \
    cur = (cur == 2) ? 0 : cur + 1;                                           \
  }

__global__ __launch_bounds__(256) void gemm_bt_splitk(
    const __hip_bfloat16* __restrict__ A,   // [M,K]
    const __hip_bfloat16* __restrict__ B,   // [N,K]
    __hip_bfloat16* __restrict__ part,      // [splits, M, N] bf16
    int M, int N, int K, int Klen)
{
  __shared__ __align__(16) __hip_bfloat16 Asl[3][128 * 32];
  __shared__ __align__(16) __hip_bfloat16 Bsl[3][128 * 32];
  const int tid  = threadIdx.x;
  const int lane = tid & 63;
  const int wave = tid >> 6;
  const int wr = wave >> 1, wc = wave & 1;
  GEMM_SWIZZLE()
  const long bm = (long)mt_ * 128, bn = (long)nt_ * 128;
  const int kstart = zt_ * Klen;

  const int srow = tid >> 2;
  const int scol = ((((tid & 3) - (tid >> 3)) & 3) << 3);
  const __hip_bfloat16* Ag0 = A + (bm + srow) * (long)K + kstart + scol;
  const __hip_bfloat16* Bg0 = B + (bn + srow) * (long)K + kstart + scol;
  const long rstride = 64l * K;

  const int fr = lane & 15;
  const int fq = lane >> 4;
  const int sw = (((fq + ((fr >> 1) & 3)) & 3) << 3);

  const floatx4 zero = {0.f, 0.f, 0.f, 0.f};
  floatx4 acc[4][4];
#pragma unroll
  for (int mi = 0; mi < 4; ++mi)
#pragma unroll
    for (int ni = 0; ni < 4; ++ni) acc[mi][ni] = zero;

  const int NI = Klen >> 5;
  GEMM_KLOOP(NI)

  __hip_bfloat16* outp = part + (size_t)zt_ * M * N;
#pragma unroll
  for (int mi = 0; mi < 4; ++mi) {
#pragma unroll
    for (int ni = 0; ni < 4; ++ni) {
      const long col = bn + wc * 64 + ni * 16 + fr;
#pragma unroll
      for (int r = 0; r < 4; ++r) {
        const long row = bm + wr * 64 + mi * 16 + fq * 4 + r;
        outp[(size_t)row * N + col] = __float2bfloat16(acc[mi][ni][r]);
      }
    }
  }
}

// ---------------------------------------------------------------------------
// V transpose: qkv v-part [token, h*64+d] -> vt[(bh*64+d)*1024 + token]
// ---------------------------------------------------------------------------
__global__ __launch_bounds__(256) void transpose_v_kernel(
    const __hip_bfloat16* __restrict__ qkv, __hip_bfloat16* __restrict__ vt)
{
  const int bh = blockIdx.y;
  const int tt = blockIdx.x;
  const int b = bh >> 4, h = bh & 15;
  __shared__ __hip_bfloat16 tile[64][65];
  const int tid = threadIdx.x;
  const int r = tid >> 2;
  const int c = (tid & 3) << 4;
  const __hip_bfloat16* src = qkv + (size_t)(b * 1024 + tt * 64 + r) * 3072 + 2048 + h * 64 + c;
  U8 u0, u1;
  u0.v = *(const shortx8*)src;
  u1.v = *(const shortx8*)(src + 8);
#pragma unroll
  for (int j = 0; j < 8; ++j) { tile[r][c + j] = u0.h[j]; tile[r][c + 8 + j] = u1.h[j]; }
  __syncthreads();
  U8 w0, w1;
#pragma unroll
  for (int j = 0; j < 8; ++j) { w0.h[j] = tile[c + j][r]; w1.h[j] = tile[c + 8 + j][r]; }
  __hip_bfloat16* dst = vt + ((size_t)bh * 64 + r) * 1024 + tt * 64 + c;
  *(shortx8*)dst       = w0.v;
  *(shortx8*)(dst + 8) = w1.v;
}

// ---------------------------------------------------------------------------
// Banded-causal flash attention. One wave per (b,h,q-tile of 16).
// ---------------------------------------------------------------------------
__global__ __launch_bounds__(256) void attn_kernel(
    const __hip_bfloat16* __restrict__ qkv,
    const __hip_bfloat16* __restrict__ vt,
    __hip_bfloat16* __restrict__ ctx)
{
  const int wave = threadIdx.x >> 6;
  const int lane = threadIdx.x & 63;
  const int gw = blockIdx.x * 4 + wave;
  const int qt = gw & 63;
  const int bh = gw >> 6;
  const int b = bh >> 4, h = bh & 15;
  const int fr = lane & 15, fq = lane >> 4;
  const int q0 = qt << 4;

  __shared__ __align__(16) __hip_bfloat16 Plds[4][16 * 32];
  __hip_bfloat16* Pw = Plds[wave];

  const __hip_bfloat16* qrow = qkv + (size_t)(b * 1024 + q0 + fr) * 3072 + h * 64;
  const shortx8 aq0 = *(const shortx8*)(qrow + fq * 8);
  const shortx8 aq1 = *(const shortx8*)(qrow + 32 + fq * 8);

  const float SC = 0.125f * 1.44269504088896f;
  float m_r[4] = {-1e30f, -1e30f, -1e30f, -1e30f};
  float l_r[4] = {0.f, 0.f, 0.f, 0.f};
  const floatx4 zero = {0.f, 0.f, 0.f, 0.f};
  floatx4 o[4];
#pragma unroll
  for (int nd = 0; nd < 4; ++nd) o[nd] = zero;

  const int kt0 = (q0 >= 255) ? ((q0 - 255) >> 5) : 0;
  const int kt1 = (q0 + 15) >> 5;
  for (int kt = kt0; kt <= kt1; ++kt) {
    const int kbase = kt << 5;
    const __hip_bfloat16* krow0 = qkv + (size_t)(b * 1024 + kbase + fr) * 3072 + 1024 + h * 64;
    const __hip_bfloat16* krow1 = krow0 + 16 * 3072;
    const shortx8 bk00 = *(const shortx8*)(krow0 + fq * 8);
    const shortx8 bk01 = *(const shortx8*)(krow0 + 32 + fq * 8);
    const shortx8 bk10 = *(const shortx8*)(krow1 + fq * 8);
    const shortx8 bk11 = *(const shortx8*)(krow1 + 32 + fq * 8);
    floatx4 s0 = zero, s1 = zero;
    s0 = __builtin_amdgcn_mfma_f32_16x16x32_bf16(aq0, bk00, s0, 0, 0, 0);
    s0 = __builtin_amdgcn_mfma_f32_16x16x32_bf16(aq1, bk01, s0, 0, 0, 0);
    s1 = __builtin_amdgcn_mfma_f32_16x16x32_bf16(aq0, bk10, s1, 0, 0, 0);
    s1 = __builtin_amdgcn_mfma_f32_16x16x32_bf16(aq1, bk11, s1, 0, 0, 0);
#pragma unroll
    for (int r = 0; r < 4; ++r) { s0[r] *= SC; s1[r] *= SC; }
    if (kbase + 31 > q0 || kbase < q0 - 240) {
#pragma unroll
      for (int r = 0; r < 4; ++r) {
        const int tq = q0 + fq * 4 + r;
        const int j0 = kbase + fr;
        const int j1 = j0 + 16;
        if (j0 > tq || j0 < tq - 255) s0[r] = -3e38f;
        if (j1 > tq || j1 < tq - 255) s1[r] = -3e38f;
      }
    }
#pragma unroll
    for (int r = 0; r < 4; ++r) {
      float vmax = fmaxf(s0[r], s1[r]);
      vmax = fmaxf(vmax, __shfl_xor(vmax, 1));
      vmax = fmaxf(vmax, __shfl_xor(vmax, 2));
      vmax = fmaxf(vmax, __shfl_xor(vmax, 4));
      vmax = fmaxf(vmax, __shfl_xor(vmax, 8));
      const float mnew = fmaxf(m_r[r], vmax);
      const float alpha = exp2f(m_r[r] - mnew);
      const float p0 = exp2f(s0[r] - mnew);
      const float p1 = exp2f(s1[r] - mnew);
      m_r[r] = mnew;
      float ps = p0 + p1;
      ps += __shfl_xor(ps, 1);
      ps += __shfl_xor(ps, 2);
      ps += __shfl_xor(ps, 4);
      ps += __shfl_xor(ps, 8);
      l_r[r] = l_r[r] * alpha + ps;
      o[0][r] *= alpha; o[1][r] *= alpha; o[2][r] *= alpha; o[3][r] *= alpha;
      Pw[(fq * 4 + r) * 32 + fr]      = __float2bfloat16(p0);
      Pw[(fq * 4 + r) * 32 + 16 + fr] = __float2bfloat16(p1);
    }
    asm volatile("s_waitcnt lgkmcnt(0)" ::: "memory");
    const shortx8 ap = *(const shortx8*)&Pw[fr * 32 + fq * 8];
#pragma unroll
    for (int nd = 0; nd < 4; ++nd) {
      const shortx8 bv = *(const shortx8*)&vt[((size_t)bh * 64 + nd * 16 + fr) * 1024 + kbase + fq * 8];
      o[nd] = __builtin_amdgcn_mfma_f32_16x16x32_bf16(ap, bv, o[nd], 0, 0, 0);
    }
    asm volatile("s_waitcnt lgkmcnt(0)" ::: "memory");
  }
#pragma unroll
  for (int nd = 0; nd < 4; ++nd)
#pragma unroll
    for (int r = 0; r < 4; ++r)
      ctx[(size_t)(b * 1024 + q0 + fq * 4 + r) * 1024 + h * 64 + nd * 16 + fr] =
          __float2bfloat16(o[nd][r] / l_r[r]);
}

// ---------------------------------------------------------------------------
// Fused split-K reduce (bf16 partials) + bias + residual + LayerNorm.
// ---------------------------------------------------------------------------
template<int S, int WB>
__global__ __launch_bounds__(256) void ln_sum_kernel(
    const __hip_bfloat16* __restrict__ part,  // [S, 4096, 1024] bf16
    const float* __restrict__ resid,          // [4096, 1024]
    const float* __restrict__ bias,           // [1024]
    const float* __restrict__ g, const float* __restrict__ be,
    float* __restrict__ outf, __hip_bfloat16* __restrict__ outb)
{
  const int row = blockIdx.x;
  const int tid = threadIdx.x;
  const size_t base = (size_t)row * 1024;
  float4 v = ((const float4*)(resid + base))[tid];
  const float4 bv = ((const float4*)bias)[tid];
  v.x += bv.x; v.y += bv.y; v.z += bv.z; v.w += bv.w;
#pragma unroll
  for (int s = 0; s < S; ++s) {
    U4 p;
    p.v = *(const unsigned long long*)&part[(size_t)s * 4096 * 1024 + base + tid * 4];
    v.x += __bfloat162float(p.h[0]);
    v.y += __bfloat162float(p.h[1]);
    v.z += __bfloat162float(p.h[2]);
    v.w += __bfloat162float(p.h[3]);
  }
  float sm = v.x + v.y + v.z + v.w;
  float ss = v.x * v.x + v.y * v.y + v.z * v.z + v.w * v.w;
#pragma unroll
  for (int off = 1; off < 64; off <<= 1) {
    sm += __shfl_xor(sm, off);
    ss += __shfl_xor(ss, off);
  }
  __shared__ float red[8];
  if ((tid & 63) == 0) { red[tid >> 6] = sm; red[4 + (tid >> 6)] = ss; }
  __syncthreads();
  sm = red[0] + red[1] + red[2] + red[3];
  ss = red[4] + red[5] + red[6] + red[7];
  const float mu = sm * (1.0f / 1024.0f);
  const float rs = rsqrtf(ss * (1.0f / 1024.0f) - mu * mu + 1e-5f);
  const float4 gg = ((const float4*)g)[tid];
  const float4 bb = ((const float4*)be)[tid];
  float4 y;
  y.x = (v.x - mu) * rs * gg.x + bb.x;
  y.y = (v.y - mu) * rs * gg.y + bb.y;
  y.z = (v.z - mu) * rs * gg.z + bb.z;
  y.w = (v.w - mu) * rs * gg.w + bb.w;
  ((float4*)(outf + base))[tid] = y;
  if (WB) {
    bf4 o4;
    o4.h[0] = __float2bfloat16(y.x);
    o4.h[1] = __float2bfloat16(y.y);
    o4.h[2] = __float2bfloat16(y.z);
    o4.h[3] = __float2bfloat16(y.w);
    *(bf4*)(outb + base + tid * 4) = o4;
  }
}

// ---------------------------------------------------------------------------
extern "C" void kernel_launch(void* const* d_in, const int* in_sizes, int n_in,
                              void* d_out, int out_size, void* d_ws, size_t ws_size,
                              hipStream_t stream) {
  const float* x    = (const float*)d_in[0];
  const float* Wqkv = (const float*)d_in[1];
  const float* bqkv = (const float*)d_in[2];
  const float* Wo   = (const float*)d_in[3];
  const float* bo   = (const float*)d_in[4];
  const float* W1   = (const float*)d_in[5];
  const float* b1   = (const float*)d_in[6];
  const float* W2   = (const float*)d_in[7];
  const float* b2   = (const float*)d_in[8];
  const float* g1   = (const float*)d_in[9];
  const float* be1  = (const float*)d_in[10];
  const float* g2   = (const float*)d_in[11];
  const float* be2  = (const float*)d_in[12];

  char* ws = (char*)d_ws;
  size_t off = 0;
  auto alloc = [&](size_t bytes) -> void* {
    void* p = ws + off;
    off += (bytes + 255) & ~(size_t)255;
    return p;
  };
  __hip_bfloat16* wqkvb = (__hip_bfloat16*)alloc(6291456);
  __hip_bfloat16* wob   = (__hip_bfloat16*)alloc(2097152);
  __hip_bfloat16* w1b   = (__hip_bfloat16*)alloc(8388608);
  __hip_bfloat16* w2b   = (__hip_bfloat16*)alloc(8388608);
  __hip_bfloat16* xb    = (__hip_bfloat16*)alloc(8388608);
  __hip_bfloat16* qkvb  = (__hip_bfloat16*)alloc(25165824);
  __hip_bfloat16* vtb   = (__hip_bfloat16*)alloc(8388608);
  __hip_bfloat16* ctxb  = (__hip_bfloat16*)alloc(8388608);
  __hip_bfloat16* part  = (__hip_bfloat16*)alloc(4u * 8388608);
  float*          x1f   = (float*)alloc(16777216);
  __hip_bfloat16* x1b   = (__hip_bfloat16*)alloc(8388608);
  __hip_bfloat16* hb    = (__hip_bfloat16*)alloc(33554432);
  (void)ws_size; (void)in_sizes; (void)n_in; (void)out_size;

  // 0. single-launch cast of x + all weights to bf16
  cast_all_kernel<<<16384, 256, 0, stream>>>(x, xb, 4096,
                                             Wqkv, wqkvb, 3072,
                                             Wo, wob, 1024,
                                             W1, w1b, 4096,
                                             W2, w2b);
  // 1. QKV projection (256x256 8-phase, 192 wgs)
  gemm256<0><<<192, 512, 0, stream>>>(xb, wqkvb, bqkv, qkvb, 4096, 3072, 1024, 12);
  // 2. attention
  transpose_v_kernel<<<dim3(16, 64), 256, 0, stream>>>(qkvb, vtb);
  attn_kernel<<<1024, 256, 0, stream>>>(qkvb, vtb, ctxb);
  // 3. output projection (split-K=2) + fused reduce+resid+LN1
  gemm_bt_splitk<<<dim3(8, 32, 2), 256, 0, stream>>>(ctxb, wob, part, 4096, 1024, 1024, 512);
  ln_sum_kernel<2, 1><<<4096, 256, 0, stream>>>(part, x, bo, g1, be1, x1f, x1b);
  // 4. FFN (FFN1: 256x256 8-phase, 256 wgs = 1/CU)
  gemm256<1><<<256, 512, 0, stream>>>(x1b, w1b, b1, hb, 4096, 4096, 1024, 16);
  gemm_bt_splitk<<<dim3(8, 32, 4), 256, 0, stream>>>(hb, w2b, part, 4096, 1024, 4096, 1024);
  ln_sum_kernel<4, 0><<<4096, 256, 0, stream>>>(part, x1f, b2, g2, be2, (float*)d_out, nullptr);
}

// Round 2
// 326.591 us; speedup vs baseline: 1.0811x; 1.0291x over previous
//
#include <hip/hip_runtime.h>
#include <hip/hip_bf16.h>

typedef __attribute__((ext_vector_type(4))) float floatx4;
typedef __attribute__((ext_vector_type(8))) short shortx8;

struct bf4 { __hip_bfloat16 h[4]; };
union U8 { shortx8 v; __hip_bfloat16 h[8]; };
union U4 { unsigned long long v; __hip_bfloat16 h[4]; };

__device__ __forceinline__ void async_copy16(const __hip_bfloat16* g, __hip_bfloat16* l) {
  __builtin_amdgcn_global_load_lds((__attribute__((address_space(1))) void*)g,
                                   (__attribute__((address_space(3))) void*)l,
                                   16, 0, 0);
}

// ---------------------------------------------------------------------------
// One-launch fp32 -> bf16 cast over 5 ranges (x, Wqkv, Wo, W1, W2).
// ---------------------------------------------------------------------------
__global__ __launch_bounds__(256) void cast_all_kernel(
    const float* __restrict__ s0, __hip_bfloat16* __restrict__ d0, int nb0,
    const float* __restrict__ s1, __hip_bfloat16* __restrict__ d1, int nb1,
    const float* __restrict__ s2, __hip_bfloat16* __restrict__ d2, int nb2,
    const float* __restrict__ s3, __hip_bfloat16* __restrict__ d3, int nb3,
    const float* __restrict__ s4, __hip_bfloat16* __restrict__ d4) {
  int b = blockIdx.x;
  const float* src; __hip_bfloat16* dst;
  if (b < nb0) { src = s0; dst = d0; }
  else { b -= nb0;
    if (b < nb1) { src = s1; dst = d1; }
    else { b -= nb1;
      if (b < nb2) { src = s2; dst = d2; }
      else { b -= nb2;
        if (b < nb3) { src = s3; dst = d3; }
        else { b -= nb3; src = s4; dst = d4; }
      }
    }
  }
  const int i = b * 256 + threadIdx.x;
  const float4 v = ((const float4*)src)[i];
  bf4 o4;
  o4.h[0] = __float2bfloat16(v.x);
  o4.h[1] = __float2bfloat16(v.y);
  o4.h[2] = __float2bfloat16(v.z);
  o4.h[3] = __float2bfloat16(v.w);
  *(bf4*)(dst + (size_t)i * 4) = o4;
}

// ===========================================================================
// 256x256 8-phase GEMM (T2 swizzle + T3/T4 counted vmcnt + T5).
// BK=64 split into two k-halves of 32; LDS ring of 4 k-half slots per
// operand ([256][32] bf16 = 16KB each; 128 KiB total). Phase = (ks, mh):
//   p0 (ks0,mh0): read B[ks0] frags + A[mh0], stage A(T+1,ks1)
//   p1 (ks0,mh1): read A[mh1],              stage B(T+1,ks1), vmcnt(8)
//   p2 (ks1,mh0): read B[ks1] frags + A[mh0], stage A(T+2,ks0)
//   p3 (ks1,mh1): read A[mh1],              stage B(T+2,ks0), vmcnt(8)
// Slot for (kt,ks) = (2*kt+ks)&3. Stage->consume distance 4-6 phases; the
// slot written at p2/p3 was last read at p0/p1 of the SAME tile, whose
// ds_reads are drained (lgkmcnt(0)) before p1's trailing barrier -> race-free.
// LDS swizzle: phys 16B-chunk = fq ^ ((row>>1)&3): the 16-lane column-slice
// read (rows R..R+15, fixed chunk) covers all 8 slots of a 128B bank cycle
// (2 lanes/slot = free). Both-sides: staging pre-swizzles the global source.
// ===========================================================================
#define STG_A(slot, kt, ks)                                                    \
  async_copy16(Ag + (size_t)(kt) * 64 + (size_t)(ks) * 32,                     \
               &As[slot][tid * 8]);                                            \
  async_copy16(Ag + (size_t)128 * K + (size_t)(kt) * 64 + (size_t)(ks) * 32,   \
               &As[slot][4096 + tid * 8]);

#define STG_B(slot, kt, ks)                                                    \
  async_copy16(Bg + (size_t)(kt) * 64 + (size_t)(ks) * 32,                     \
               &Bs[slot][tid * 8]);                                            \
  async_copy16(Bg + (size_t)128 * K + (size_t)(kt) * 64 + (size_t)(ks) * 32,   \
               &Bs[slot][4096 + tid * 8]);

#define G256_PHASE(SLOT, MH, BLOAD, STAGE_CODE, WAIT_CODE)                     \
  {                                                                            \
    const __hip_bfloat16* Asl = As[SLOT];                                      \
    const __hip_bfloat16* Bsl = Bs[SLOT];                                      \
    if (BLOAD) {                                                               \
      _Pragma("unroll")                                                        \
      for (int ni = 0; ni < 4; ++ni)                                           \
        bfr[ni] = *(const shortx8*)&Bsl[brd + ni * 512];                       \
    }                                                                          \
    shortx8 afr[4];                                                            \
    _Pragma("unroll")                                                          \
    for (int mi4 = 0; mi4 < 4; ++mi4)                                          \
      afr[mi4] = *(const shortx8*)&Asl[ard + ((MH) * 4 + mi4) * 512];          \
    STAGE_CODE;                                                                \
    WAIT_CODE;                                                                 \
    __builtin_amdgcn_s_barrier();                                              \
    asm volatile("s_waitcnt lgkmcnt(0)" ::: "memory");                         \
    __builtin_amdgcn_sched_barrier(0);                                         \
    __builtin_amdgcn_s_setprio(1);                                             \
    _Pragma("unroll")                                                          \
    for (int mi4 = 0; mi4 < 4; ++mi4)                                          \
      _Pragma("unroll")                                                        \
      for (int ni = 0; ni < 4; ++ni)                                           \
        acc[(MH) * 4 + mi4][ni] = __builtin_amdgcn_mfma_f32_16x16x32_bf16(     \
            afr[mi4], bfr[ni], acc[(MH) * 4 + mi4][ni], 0, 0, 0);              \
    __builtin_amdgcn_s_setprio(0);                                             \
    __builtin_amdgcn_s_barrier();                                              \
  }

#define G256_KLOOP()                                                           \
  STG_A(0, 0, 0) STG_B(0, 0, 0)                                                \
  STG_A(1, 0, 1) STG_B(1, 0, 1)                                                \
  STG_A(2, 1, 0) STG_B(2, 1, 0)                                                \
  asm volatile("s_waitcnt vmcnt(8)" ::: "memory");                             \
  __builtin_amdgcn_s_barrier();                                                \
  shortx8 bfr[4];                                                              \
  for (int T = 0; T < NKT; ++T) {                                              \
    const int s00 = (2 * T) & 3;                                               \
    const int s01 = (2 * T + 1) & 3;                                           \
    const int sn1 = (2 * T + 3) & 3;   /* (T+1, ks1) */                        \
    const int sn0 = (2 * T + 4) & 3;   /* (T+2, ks0) */                        \
    const bool st1 = (T + 1 < NKT);                                            \
    const bool st2 = (T + 2 < NKT);                                            \
    G256_PHASE(s00, 0, true,                                                   \
               { if (st1) { STG_A(sn1, T + 1, 1) } },                          \
               {})                                                             \
    G256_PHASE(s00, 1, false,                                                  \
               { if (st1) { STG_B(sn1, T + 1, 1) } },                          \
               { if (st1) { asm volatile("s_waitcnt vmcnt(8)" ::: "memory"); } \
                 else     { asm volatile("s_waitcnt vmcnt(0)" ::: "memory"); } })\
    G256_PHASE(s01, 0, true,                                                   \
               { if (st2) { STG_A(sn0, T + 2, 0) } },                          \
               {})                                                             \
    G256_PHASE(s01, 1, false,                                                  \
               { if (st2) { STG_B(sn0, T + 2, 0) } },                          \
               { if (st2)      { asm volatile("s_waitcnt vmcnt(8)" ::: "memory"); }\
                 else if (st1) { asm volatile("s_waitcnt vmcnt(4)" ::: "memory"); } })\
  }

// C[M,N] = A[M,K] * B[N,K]^T, bf16 in, fp32 acc, 256x256 tile, 512 threads.
// EPI: 0 = +bias -> bf16; 1 = +bias, gelu -> bf16
template<int EPI>
__global__ __launch_bounds__(512, 2) void gemm256(
    const __hip_bfloat16* __restrict__ A,   // [M,K]
    const __hip_bfloat16* __restrict__ B,   // [N,K]
    const float* __restrict__ bias,         // [N]
    __hip_bfloat16* __restrict__ outb,
    int M, int N, int K, int NT)
{
  __shared__ __align__(16) __hip_bfloat16 As[4][256 * 32];
  __shared__ __align__(16) __hip_bfloat16 Bs[4][256 * 32];
  const int tid  = threadIdx.x;
  const int lane = tid & 63;
  const int wave = tid >> 6;        // 0..7
  const int wr = wave >> 2;         // 0..1 (M half, 128 rows)
  const int wc = wave & 3;          // 0..3 (N quarter, 64 cols)
  const int fr = lane & 15;
  const int fq = lane >> 4;         // 0..3

  // bijective XCD swizzle (nwg % 8 == 0 for all call sites)
  const int nwg = gridDim.x;
  const int cpx = nwg >> 3;
  const int swz = (blockIdx.x & 7) * cpx + (blockIdx.x >> 3);
  const int mt = swz / NT, nt = swz % NT;
  const long bm = (long)mt * 256, bn = (long)nt * 256;

  // staging: thread t covers linear LDS 16B-chunk (i*512+t) of a k-half slot;
  // row = i*128 + (t>>2), phys chunk = t&3 -> logical chunk pre-swizzled.
  const int srow = tid >> 2;                       // 0..127
  const int sch  = (tid & 3) ^ ((tid >> 3) & 3);   // source k-chunk (involution)
  const __hip_bfloat16* Ag = A + (bm + srow) * (size_t)K + sch * 8;
  const __hip_bfloat16* Bg = B + (bn + srow) * (size_t)K + sch * 8;

  // ds_read bases (elements), swizzled chunk = fq ^ ((row>>1)&3) = fq ^ ((fr>>1)&3)
  const int swc = (fq ^ ((fr >> 1) & 3)) << 3;
  const int ard = (wr * 128 + fr) * 32 + swc;
  const int brd = (wc * 64 + fr) * 32 + swc;

  const floatx4 zero = {0.f, 0.f, 0.f, 0.f};
  floatx4 acc[8][4];
#pragma unroll
  for (int mi = 0; mi < 8; ++mi)
#pragma unroll
    for (int ni = 0; ni < 4; ++ni) acc[mi][ni] = zero;

  const int NKT = K >> 6;           // K-tiles of 64 (>=2 at all call sites)
  G256_KLOOP()

  // epilogue: C/D layout col = lane&15, row = (lane>>4)*4 + reg
#pragma unroll
  for (int mi = 0; mi < 8; ++mi) {
#pragma unroll
    for (int ni = 0; ni < 4; ++ni) {
      const long col = bn + wc * 64 + ni * 16 + fr;
      const float bv = bias[col];
#pragma unroll
      for (int r = 0; r < 4; ++r) {
        const long row = bm + wr * 128 + mi * 16 + fq * 4 + r;
        float v = acc[mi][ni][r] + bv;
        if (EPI == 1) {
          const float u = v + 0.044715f * v * v * v;
          v = v / (1.0f + __expf(-1.5957691216057308f * u));
        }
        outb[(size_t)row * N + col] = __float2bfloat16(v);
      }
    }
  }
}

// ---------------------------------------------------------------------------
// 256x256 8-phase split-K GEMM -> bf16 partials [SPLITS, M, N].
// Grid = TPS*SPLITS wgs (TPS = (M/256)*(N/256)); swz%8==0 bijective XCD
// swizzle; one XCD chunk covers one split's operand slabs (L2-resident).
// ---------------------------------------------------------------------------
__global__ __launch_bounds__(512, 2) void gemm256_splitk(
    const __hip_bfloat16* __restrict__ A,   // [M,K]
    const __hip_bfloat16* __restrict__ B,   // [N,K]
    __hip_bfloat16* __restrict__ part,      // [SPLITS, M, N]
    int M, int N, int K, int Klen, int NT, int TPS)
{
  __shared__ __align__(16) __hip_bfloat16 As[4][256 * 32];
  __shared__ __align__(16) __hip_bfloat16 Bs[4][256 * 32];
  const int tid  = threadIdx.x;
  const int lane = tid & 63;
  const int wave = tid >> 6;
  const int wr = wave >> 2;
  const int wc = wave & 3;
  const int fr = lane & 15;
  const int fq = lane >> 4;

  const int nwg = gridDim.x;
  const int cpx = nwg >> 3;
  const int swz = (blockIdx.x & 7) * cpx + (blockIdx.x >> 3);
  const int zt = swz / TPS;
  const int tile = swz % TPS;
  const int mt = tile / NT, nt = tile % NT;
  const long bm = (long)mt * 256, bn = (long)nt * 256;
  const int kstart = zt * Klen;

  const int srow = tid >> 2;
  const int sch  = (tid & 3) ^ ((tid >> 3) & 3);
  const __hip_bfloat16* Ag = A + (bm + srow) * (size_t)K + kstart + sch * 8;
  const __hip_bfloat16* Bg = B + (bn + srow) * (size_t)K + kstart + sch * 8;

  const int swc = (fq ^ ((fr >> 1) & 3)) << 3;
  const int ard = (wr * 128 + fr) * 32 + swc;
  const int brd = (wc * 64 + fr) * 32 + swc;

  const floatx4 zero = {0.f, 0.f, 0.f, 0.f};
  floatx4 acc[8][4];
#pragma unroll
  for (int mi = 0; mi < 8; ++mi)
#pragma unroll
    for (int ni = 0; ni < 4; ++ni) acc[mi][ni] = zero;

  const int NKT = Klen >> 6;
  G256_KLOOP()

  __hip_bfloat16* outp = part + (size_t)zt * M * N;
#pragma unroll
  for (int mi = 0; mi < 8; ++mi) {
#pragma unroll
    for (int ni = 0; ni < 4; ++ni) {
      const long col = bn + wc * 64 + ni * 16 + fr;
#pragma unroll
      for (int r = 0; r < 4; ++r) {
        const long row = bm + wr * 128 + mi * 16 + fq * 4 + r;
        outp[(size_t)row * N + col] = __float2bfloat16(acc[mi][ni][r]);
      }
    }
  }
}

// ---------------------------------------------------------------------------
// 128x128 split-K GEMM (round 7 structure) -> bf16 partials. (attn-out proj)
// ---------------------------------------------------------------------------
#define GEMM_SWIZZLE()                                                        \
  const int flat = blockIdx.x + gridDim.x * (blockIdx.y + 32 * blockIdx.z);   \
  const int xcd_ = flat & 7;                                                  \
  int rsw_ = flat >> 3;                                                       \
  const int mt_ = xcd_ * 4 + (rsw_ & 3);                                      \
  rsw_ >>= 2;                                                                 \
  const int nt_ = rsw_ % gridDim.x;                                           \
  const int zt_ = rsw_ / gridDim.x;

#define GEMM_STAGE(buf, koff)                                      \
  async_copy16(Ag0 + (koff),           &Asl[buf][tid * 8]);        \
  async_copy16(Ag0 + (koff) + rstride, &Asl[buf][tid * 8 + 2048]); \
  async_copy16(Bg0 + (koff),           &Bsl[buf][tid * 8]);        \
  async_copy16(Bg0 + (koff) + rstride, &Bsl[buf][tid * 8 + 2048]);

#define GEMM_KLOOP(NI)                                                        \
  GEMM_STAGE(0, 0)                                                            \
  GEMM_STAGE(1, 32)                                                           \
  int cur = 0;                                                                \
  for (int it = 0; it < (NI); ++it) {                                         \
    if (it + 2 < (NI)) {                                                      \
      const int nb = (cur >= 1) ? cur - 1 : cur + 2;  /* (cur+2)%3 */         \
      GEMM_STAGE(nb, (it + 2) * 32)                                           \
      asm volatile("s_waitcnt vmcnt(8)" ::: "memory");                        \
    } else if (it + 1 < (NI)) {                                               \
      asm volatile("s_waitcnt vmcnt(4)" ::: "memory");                        \
    } else {                                                                  \
      asm volatile("s_waitcnt vmcnt(0)" ::: "memory");                        \
    }                                                                         \
    asm volatile("s_barrier" ::: "memory");                                   \
    const __hip_bfloat16* Ac = Asl[cur];                                      \
    const __hip_bfloat16* Bc = Bsl[cur];                                      \
    shortx8 afr[4], bfr[4];                                                   \
    _Pragma("unroll")                                                         \
    for (int i = 0; i < 4; ++i) {                                             \
      afr[i] = *(const shortx8*)&Ac[(wr * 64 + i * 16 + fr) * 32 + sw];       \
      bfr[i] = *(const shortx8*)&Bc[(wc * 64 + i * 16 + fr) * 32 + sw];       \
    }                                                                         \
    _Pragma("unroll")                                                         \
    for (int mi = 0; mi < 4; ++mi)                                            \
      _Pragma("unroll")                                                       \
      for (int ni = 0; ni < 4; ++ni)                                          \
        acc[mi][ni] = __builtin_amdgcn_mfma_f32_16x16x32_bf16(                \
            afr[mi], bfr[ni], acc[mi][ni], 0, 0, 0);                          \
    asm volatile("s_barrier" ::: "memory");                                   \
    cur = (cur == 2) ? 0 : cur + 1;                                           \
  }

__global__ __launch_bounds__(256) void gemm_bt_splitk(
    const __hip_bfloat16* __restrict__ A,   // [M,K]
    const __hip_bfloat16* __restrict__ B,   // [N,K]
    __hip_bfloat16* __restrict__ part,      // [splits, M, N] bf16
    int M, int N, int K, int Klen)
{
  __shared__ __align__(16) __hip_bfloat16 Asl[3][128 * 32];
  __shared__ __align__(16) __hip_bfloat16 Bsl[3][128 * 32];
  const int tid  = threadIdx.x;
  const int lane = tid & 63;
  const int wave = tid >> 6;
  const int wr = wave >> 1, wc = wave & 1;
  GEMM_SWIZZLE()
  const long bm = (long)mt_ * 128, bn = (long)nt_ * 128;
  const int kstart = zt_ * Klen;

  const int srow = tid >> 2;
  const int scol = ((((tid & 3) - (tid >> 3)) & 3) << 3);
  const __hip_bfloat16* Ag0 = A + (bm + srow) * (long)K + kstart + scol;
  const __hip_bfloat16* Bg0 = B + (bn + srow) * (long)K + kstart + scol;
  const long rstride = 64l * K;

  const int fr = lane & 15;
  const int fq = lane >> 4;
  const int sw = (((fq + ((fr >> 1) & 3)) & 3) << 3);

  const floatx4 zero = {0.f, 0.f, 0.f, 0.f};
  floatx4 acc[4][4];
#pragma unroll
  for (int mi = 0; mi < 4; ++mi)
#pragma unroll
    for (int ni = 0; ni < 4; ++ni) acc[mi][ni] = zero;

  const int NI = Klen >> 5;
  GEMM_KLOOP(NI)

  __hip_bfloat16* outp = part + (size_t)zt_ * M * N;
#pragma unroll
  for (int mi = 0; mi < 4; ++mi) {
#pragma unroll
    for (int ni = 0; ni < 4; ++ni) {
      const long col = bn + wc * 64 + ni * 16 + fr;
#pragma unroll
      for (int r = 0; r < 4; ++r) {
        const long row = bm + wr * 64 + mi * 16 + fq * 4 + r;
        outp[(size_t)row * N + col] = __float2bfloat16(acc[mi][ni][r]);
      }
    }
  }
}

// ---------------------------------------------------------------------------
// V transpose: qkv v-part [token, h*64+d] -> vt[(bh*64+d)*1024 + token]
// ---------------------------------------------------------------------------
__global__ __launch_bounds__(256) void transpose_v_kernel(
    const __hip_bfloat16* __restrict__ qkv, __hip_bfloat16* __restrict__ vt)
{
  const int bh = blockIdx.y;
  const int tt = blockIdx.x;
  const int b = bh >> 4, h = bh & 15;
  __shared__ __hip_bfloat16 tile[64][65];
  const int tid = threadIdx.x;
  const int r = tid >> 2;
  const int c = (tid & 3) << 4;
  const __hip_bfloat16* src = qkv + (size_t)(b * 1024 + tt * 64 + r) * 3072 + 2048 + h * 64 + c;
  U8 u0, u1;
  u0.v = *(const shortx8*)src;
  u1.v = *(const shortx8*)(src + 8);
#pragma unroll
  for (int j = 0; j < 8; ++j) { tile[r][c + j] = u0.h[j]; tile[r][c + 8 + j] = u1.h[j]; }
  __syncthreads();
  U8 w0, w1;
#pragma unroll
  for (int j = 0; j < 8; ++j) { w0.h[j] = tile[c + j][r]; w1.h[j] = tile[c + 8 + j][r]; }
  __hip_bfloat16* dst = vt + ((size_t)bh * 64 + r) * 1024 + tt * 64 + c;
  *(shortx8*)dst       = w0.v;
  *(shortx8*)(dst + 8) = w1.v;
}

// ---------------------------------------------------------------------------
// Banded-causal flash attention. One wave per (b,h,q-tile of 16).
// ---------------------------------------------------------------------------
__global__ __launch_bounds__(256) void attn_kernel(
    const __hip_bfloat16* __restrict__ qkv,
    const __hip_bfloat16* __restrict__ vt,
    __hip_bfloat16* __restrict__ ctx)
{
  const int wave = threadIdx.x >> 6;
  const int lane = threadIdx.x & 63;
  const int gw = blockIdx.x * 4 + wave;
  const int qt = gw & 63;
  const int bh = gw >> 6;
  const int b = bh >> 4, h = bh & 15;
  const int fr = lane & 15, fq = lane >> 4;
  const int q0 = qt << 4;

  __shared__ __align__(16) __hip_bfloat16 Plds[4][16 * 32];
  __hip_bfloat16* Pw = Plds[wave];

  const __hip_bfloat16* qrow = qkv + (size_t)(b * 1024 + q0 + fr) * 3072 + h * 64;
  const shortx8 aq0 = *(const shortx8*)(qrow + fq * 8);
  const shortx8 aq1 = *(const shortx8*)(qrow + 32 + fq * 8);

  const float SC = 0.125f * 1.44269504088896f;
  float m_r[4] = {-1e30f, -1e30f, -1e30f, -1e30f};
  float l_r[4] = {0.f, 0.f, 0.f, 0.f};
  const floatx4 zero = {0.f, 0.f, 0.f, 0.f};
  floatx4 o[4];
#pragma unroll
  for (int nd = 0; nd < 4; ++nd) o[nd] = zero;

  const int kt0 = (q0 >= 255) ? ((q0 - 255) >> 5) : 0;
  const int kt1 = (q0 + 15) >> 5;
  for (int kt = kt0; kt <= kt1; ++kt) {
    const int kbase = kt << 5;
    const __hip_bfloat16* krow0 = qkv + (size_t)(b * 1024 + kbase + fr) * 3072 + 1024 + h * 64;
    const __hip_bfloat16* krow1 = krow0 + 16 * 3072;
    const shortx8 bk00 = *(const shortx8*)(krow0 + fq * 8);
    const shortx8 bk01 = *(const shortx8*)(krow0 + 32 + fq * 8);
    const shortx8 bk10 = *(const shortx8*)(krow1 + fq * 8);
    const shortx8 bk11 = *(const shortx8*)(krow1 + 32 + fq * 8);
    floatx4 s0 = zero, s1 = zero;
    s0 = __builtin_amdgcn_mfma_f32_16x16x32_bf16(aq0, bk00, s0, 0, 0, 0);
    s0 = __builtin_amdgcn_mfma_f32_16x16x32_bf16(aq1, bk01, s0, 0, 0, 0);
    s1 = __builtin_amdgcn_mfma_f32_16x16x32_bf16(aq0, bk10, s1, 0, 0, 0);
    s1 = __builtin_amdgcn_mfma_f32_16x16x32_bf16(aq1, bk11, s1, 0, 0, 0);
#pragma unroll
    for (int r = 0; r < 4; ++r) { s0[r] *= SC; s1[r] *= SC; }
    if (kbase + 31 > q0 || kbase < q0 - 240) {
#pragma unroll
      for (int r = 0; r < 4; ++r) {
        const int tq = q0 + fq * 4 + r;
        const int j0 = kbase + fr;
        const int j1 = j0 + 16;
        if (j0 > tq || j0 < tq - 255) s0[r] = -3e38f;
        if (j1 > tq || j1 < tq - 255) s1[r] = -3e38f;
      }
    }
#pragma unroll
    for (int r = 0; r < 4; ++r) {
      float vmax = fmaxf(s0[r], s1[r]);
      vmax = fmaxf(vmax, __shfl_xor(vmax, 1));
      vmax = fmaxf(vmax, __shfl_xor(vmax, 2));
      vmax = fmaxf(vmax, __shfl_xor(vmax, 4));
      vmax = fmaxf(vmax, __shfl_xor(vmax, 8));
      const float mnew = fmaxf(m_r[r], vmax);
      const float alpha = exp2f(m_r[r] - mnew);
      const float p0 = exp2f(s0[r] - mnew);
      const float p1 = exp2f(s1[r] - mnew);
      m_r[r] = mnew;
      float ps = p0 + p1;
      ps += __shfl_xor(ps, 1);
      ps += __shfl_xor(ps, 2);
      ps += __shfl_xor(ps, 4);
      ps += __shfl_xor(ps, 8);
      l_r[r] = l_r[r] * alpha + ps;
      o[0][r] *= alpha; o[1][r] *= alpha; o[2][r] *= alpha; o[3][r] *= alpha;
      Pw[(fq * 4 + r) * 32 + fr]      = __float2bfloat16(p0);
      Pw[(fq * 4 + r) * 32 + 16 + fr] = __float2bfloat16(p1);
    }
    asm volatile("s_waitcnt lgkmcnt(0)" ::: "memory");
    const shortx8 ap = *(const shortx8*)&Pw[fr * 32 + fq * 8];
#pragma unroll
    for (int nd = 0; nd < 4; ++nd) {
      const shortx8 bv = *(const shortx8*)&vt[((size_t)bh * 64 + nd * 16 + fr) * 1024 + kbase + fq * 8];
      o[nd] = __builtin_amdgcn_mfma_f32_16x16x32_bf16(ap, bv, o[nd], 0, 0, 0);
    }
    asm volatile("s_waitcnt lgkmcnt(0)" ::: "memory");
  }
#pragma unroll
  for (int nd = 0; nd < 4; ++nd)
#pragma unroll
    for (int r = 0; r < 4; ++r)
      ctx[(size_t)(b * 1024 + q0 + fq * 4 + r) * 1024 + h * 64 + nd * 16 + fr] =
          __float2bfloat16(o[nd][r] / l_r[r]);
}

// ---------------------------------------------------------------------------
// Fused split-K reduce (bf16 partials) + bias + residual + LayerNorm.
// ---------------------------------------------------------------------------
template<int S, int WB>
__global__ __launch_bounds__(256) void ln_sum_kernel(
    const __hip_bfloat16* __restrict__ part,  // [S, 4096, 1024] bf16
    const float* __restrict__ resid,          // [4096, 1024]
    const float* __restrict__ bias,           // [1024]
    const float* __restrict__ g, const float* __restrict__ be,
    float* __restrict__ outf, __hip_bfloat16* __restrict__ outb)
{
  const int row = blockIdx.x;
  const int tid = threadIdx.x;
  const size_t base = (size_t)row * 1024;
  float4 v = ((const float4*)(resid + base))[tid];
  const float4 bv = ((const float4*)bias)[tid];
  v.x += bv.x; v.y += bv.y; v.z += bv.z; v.w += bv.w;
#pragma unroll
  for (int s = 0; s < S; ++s) {
    U4 p;
    p.v = *(const unsigned long long*)&part[(size_t)s * 4096 * 1024 + base + tid * 4];
    v.x += __bfloat162float(p.h[0]);
    v.y += __bfloat162float(p.h[1]);
    v.z += __bfloat162float(p.h[2]);
    v.w += __bfloat162float(p.h[3]);
  }
  float sm = v.x + v.y + v.z + v.w;
  float ss = v.x * v.x + v.y * v.y + v.z * v.z + v.w * v.w;
#pragma unroll
  for (int off = 1; off < 64; off <<= 1) {
    sm += __shfl_xor(sm, off);
    ss += __shfl_xor(ss, off);
  }
  __shared__ float red[8];
  if ((tid & 63) == 0) { red[tid >> 6] = sm; red[4 + (tid >> 6)] = ss; }
  __syncthreads();
  sm = red[0] + red[1] + red[2] + red[3];
  ss = red[4] + red[5] + red[6] + red[7];
  const float mu = sm * (1.0f / 1024.0f);
  const float rs = rsqrtf(ss * (1.0f / 1024.0f) - mu * mu + 1e-5f);
  const float4 gg = ((const float4*)g)[tid];
  const float4 bb = ((const float4*)be)[tid];
  float4 y;
  y.x = (v.x - mu) * rs * gg.x + bb.x;
  y.y = (v.y - mu) * rs * gg.y + bb.y;
  y.z = (v.z - mu) * rs * gg.z + bb.z;
  y.w = (v.w - mu) * rs * gg.w + bb.w;
  ((float4*)(outf + base))[tid] = y;
  if (WB) {
    bf4 o4;
    o4.h[0] = __float2bfloat16(y.x);
    o4.h[1] = __float2bfloat16(y.y);
    o4.h[2] = __float2bfloat16(y.z);
    o4.h[3] = __float2bfloat16(y.w);
    *(bf4*)(outb + base + tid * 4) = o4;
  }
}

// ---------------------------------------------------------------------------
extern "C" void kernel_launch(void* const* d_in, const int* in_sizes, int n_in,
                              void* d_out, int out_size, void* d_ws, size_t ws_size,
                              hipStream_t stream) {
  const float* x    = (const float*)d_in[0];
  const float* Wqkv = (const float*)d_in[1];
  const float* bqkv = (const float*)d_in[2];
  const float* Wo   = (const float*)d_in[3];
  const float* bo   = (const float*)d_in[4];
  const float* W1   = (const float*)d_in[5];
  const float* b1   = (const float*)d_in[6];
  const float* W2   = (const float*)d_in[7];
  const float* b2   = (const float*)d_in[8];
  const float* g1   = (const float*)d_in[9];
  const float* be1  = (const float*)d_in[10];
  const float* g2   = (const float*)d_in[11];
  const float* be2  = (const float*)d_in[12];

  char* ws = (char*)d_ws;
  size_t off = 0;
  auto alloc = [&](size_t bytes) -> void* {
    void* p = ws + off;
    off += (bytes + 255) & ~(size_t)255;
    return p;
  };
  __hip_bfloat16* wqkvb = (__hip_bfloat16*)alloc(6291456);
  __hip_bfloat16* wob   = (__hip_bfloat16*)alloc(2097152);
  __hip_bfloat16* w1b   = (__hip_bfloat16*)alloc(8388608);
  __hip_bfloat16* w2b   = (__hip_bfloat16*)alloc(8388608);
  __hip_bfloat16* xb    = (__hip_bfloat16*)alloc(8388608);
  __hip_bfloat16* qkvb  = (__hip_bfloat16*)alloc(25165824);
  __hip_bfloat16* vtb   = (__hip_bfloat16*)alloc(8388608);
  __hip_bfloat16* ctxb  = (__hip_bfloat16*)alloc(8388608);
  __hip_bfloat16* part  = (__hip_bfloat16*)alloc(4u * 8388608);
  float*          x1f   = (float*)alloc(16777216);
  __hip_bfloat16* x1b   = (__hip_bfloat16*)alloc(8388608);
  __hip_bfloat16* hb    = (__hip_bfloat16*)alloc(33554432);
  (void)ws_size; (void)in_sizes; (void)n_in; (void)out_size;

  // 0. single-launch cast of x + all weights to bf16
  cast_all_kernel<<<16384, 256, 0, stream>>>(x, xb, 4096,
                                             Wqkv, wqkvb, 3072,
                                             Wo, wob, 1024,
                                             W1, w1b, 4096,
                                             W2, w2b);
  // 1. QKV projection (256x256 8-phase, 192 wgs)
  gemm256<0><<<192, 512, 0, stream>>>(xb, wqkvb, bqkv, qkvb, 4096, 3072, 1024, 12);
  // 2. attention
  transpose_v_kernel<<<dim3(16, 64), 256, 0, stream>>>(qkvb, vtb);
  attn_kernel<<<1024, 256, 0, stream>>>(qkvb, vtb, ctxb);
  // 3. output projection (split-K=2) + fused reduce+resid+LN1
  gemm_bt_splitk<<<dim3(8, 32, 2), 256, 0, stream>>>(ctxb, wob, part, 4096, 1024, 1024, 512);
  ln_sum_kernel<2, 1><<<4096, 256, 0, stream>>>(part, x, bo, g1, be1, x1f, x1b);
  // 4. FFN (FFN1: 256x256 8-phase, 256 wgs = 1/CU)
  gemm256<1><<<256, 512, 0, stream>>>(x1b, w1b, b1, hb, 4096, 4096, 1024, 16);
  // FFN2: 256x256 8-phase split-K=4 (64 tiles x 4 splits = 256 wgs)
  gemm256_splitk<<<256, 512, 0, stream>>>(hb, w2b, part, 4096, 1024, 4096, 1024, 4, 64);
  ln_sum_kernel<4, 0><<<4096, 256, 0, stream>>>(part, x1f, b2, g2, be2, (float*)d_out, nullptr);
}

// Round 3
// 321.237 us; speedup vs baseline: 1.0991x; 1.0167x over previous
//
#include <hip/hip_runtime.h>
#include <hip/hip_bf16.h>

typedef __attribute__((ext_vector_type(4))) float floatx4;
typedef __attribute__((ext_vector_type(8))) short shortx8;

struct bf4 { __hip_bfloat16 h[4]; };
union U8 { shortx8 v; __hip_bfloat16 h[8]; };
union U4 { unsigned long long v; __hip_bfloat16 h[4]; };

__device__ __forceinline__ void async_copy16(const __hip_bfloat16* g, __hip_bfloat16* l) {
  __builtin_amdgcn_global_load_lds((__attribute__((address_space(1))) void*)g,
                                   (__attribute__((address_space(3))) void*)l,
                                   16, 0, 0);
}

// ---------------------------------------------------------------------------
// One-launch fp32 -> bf16 cast over 5 ranges (x, Wqkv, Wo, W1, W2).
// ---------------------------------------------------------------------------
__global__ __launch_bounds__(256) void cast_all_kernel(
    const float* __restrict__ s0, __hip_bfloat16* __restrict__ d0, int nb0,
    const float* __restrict__ s1, __hip_bfloat16* __restrict__ d1, int nb1,
    const float* __restrict__ s2, __hip_bfloat16* __restrict__ d2, int nb2,
    const float* __restrict__ s3, __hip_bfloat16* __restrict__ d3, int nb3,
    const float* __restrict__ s4, __hip_bfloat16* __restrict__ d4) {
  int b = blockIdx.x;
  const float* src; __hip_bfloat16* dst;
  if (b < nb0) { src = s0; dst = d0; }
  else { b -= nb0;
    if (b < nb1) { src = s1; dst = d1; }
    else { b -= nb1;
      if (b < nb2) { src = s2; dst = d2; }
      else { b -= nb2;
        if (b < nb3) { src = s3; dst = d3; }
        else { b -= nb3; src = s4; dst = d4; }
      }
    }
  }
  const int i = b * 256 + threadIdx.x;
  const float4 v = ((const float4*)src)[i];
  bf4 o4;
  o4.h[0] = __float2bfloat16(v.x);
  o4.h[1] = __float2bfloat16(v.y);
  o4.h[2] = __float2bfloat16(v.z);
  o4.h[3] = __float2bfloat16(v.w);
  *(bf4*)(dst + (size_t)i * 4) = o4;
}

// ===========================================================================
// Round 9: 256x256 8-phase GEMM with ONE-PHASE-AHEAD register prefetch.
// LDS ring of 4 k-half slots per operand ([256][32] bf16, 128 KiB total).
// Each phase: [barrier][vmcnt at p0/p2][issue ds_reads for NEXT phase]
// [issue gload_lds stage][sched_barrier][MFMA on PREV phase's frags].
// The compiler inserts a COUNTED lgkm wait before the MFMA (just-issued
// reads stay outstanding) -> LDS-read time hides under the MFMA cluster.
// Race ledger:
//  - slot validity: reads of slot staged at (T-1 p0/p1) first issue at
//    p1-top(T); every wave runs vmcnt(4) at p0-top(T) (ensures those 4
//    oldest loads done; 4 newest = T-1 p2/p3 may fly), then bar(p1)
//    publishes. Same for p2-top(T) covering (T-1 p2/p3) before p3-top
//    reads. Tail: final tile uses vmcnt(0) (fewer loads in flight, the
//    counted wait would be a no-op -> must drain).
//  - slot reuse: a slot's last ds_reads issue at phase i; the reading
//    wave's compiler-inserted counted lgkm at phase i+1 drains them
//    before its MFMA, hence before it reaches bar(i+2); restage of that
//    slot happens at phase >= i+2, after bar -> no overwrite race.
// LDS swizzle unchanged (verified conflicts=0): phys chunk = fq^((row>>1)&3),
// staging pre-swizzles the global source column.
// ===========================================================================
#define STG_A(slot, kt, ks)                                                    \
  async_copy16(Ag + (size_t)(kt) * 64 + (size_t)(ks) * 32,                     \
               &As[slot][tid * 8]);                                            \
  async_copy16(Ag + (size_t)128 * K + (size_t)(kt) * 64 + (size_t)(ks) * 32,   \
               &As[slot][4096 + tid * 8]);

#define STG_B(slot, kt, ks)                                                    \
  async_copy16(Bg + (size_t)(kt) * 64 + (size_t)(ks) * 32,                     \
               &Bs[slot][tid * 8]);                                            \
  async_copy16(Bg + (size_t)128 * K + (size_t)(kt) * 64 + (size_t)(ks) * 32,   \
               &Bs[slot][4096 + tid * 8]);

#define G256_READ_A(dst, slot, mh)                                             \
  _Pragma("unroll")                                                            \
  for (int i_ = 0; i_ < 4; ++i_)                                               \
    dst[i_] = *(const shortx8*)&As[slot][ard + ((mh) * 4 + i_) * 512];

#define G256_READ_B(dst, slot)                                                 \
  _Pragma("unroll")                                                            \
  for (int i_ = 0; i_ < 4; ++i_)                                               \
    dst[i_] = *(const shortx8*)&Bs[slot][brd + i_ * 512];

#define G256_MFMA(afr, bfr, MH)                                                \
  __builtin_amdgcn_sched_barrier(0);                                           \
  __builtin_amdgcn_s_setprio(1);                                               \
  _Pragma("unroll")                                                            \
  for (int mi_ = 0; mi_ < 4; ++mi_)                                            \
    _Pragma("unroll")                                                          \
    for (int ni_ = 0; ni_ < 4; ++ni_)                                          \
      acc[(MH) * 4 + mi_][ni_] = __builtin_amdgcn_mfma_f32_16x16x32_bf16(      \
          afr[mi_], bfr[ni_], acc[(MH) * 4 + mi_][ni_], 0, 0, 0);              \
  __builtin_amdgcn_s_setprio(0);                                               \
  __builtin_amdgcn_sched_barrier(0);

#define G256_BAR() asm volatile("s_barrier" ::: "memory")

#define G256_KLOOP()                                                           \
  STG_A(0, 0, 0) STG_B(0, 0, 0)                                                \
  STG_A(1, 0, 1) STG_B(1, 0, 1)                                                \
  STG_A(2, 1, 0) STG_B(2, 1, 0)                                                \
  asm volatile("s_waitcnt vmcnt(8)" ::: "memory");                             \
  G256_BAR();                                                                  \
  shortx8 a0[4], a1[4], bE[4], bO[4];                                          \
  G256_READ_B(bE, 0)                                                           \
  G256_READ_A(a0, 0, 0)                                                        \
  for (int T = 0; T < NKT; ++T) {                                              \
    const int s00 = (2 * T) & 3;                                               \
    const int s01 = (2 * T + 1) & 3;                                           \
    const int sx  = (2 * T + 2) & 3;   /* s00 of T+1 */                        \
    const int sn1 = (2 * T + 3) & 3;   /* (T+1, ks1) */                        \
    const int sn0 = (2 * T + 4) & 3;   /* (T+2, ks0) */                        \
    const bool st1 = (T + 1 < NKT);                                            \
    const bool st2 = (T + 2 < NKT);                                            \
    /* p0 */                                                                   \
    G256_BAR();                                                                \
    if (st1) { asm volatile("s_waitcnt vmcnt(4)" ::: "memory"); }              \
    else     { asm volatile("s_waitcnt vmcnt(0)" ::: "memory"); }              \
    G256_READ_A(a1, s00, 1)                                                    \
    if (st1) { STG_A(sn1, T + 1, 1) }                                          \
    G256_MFMA(a0, bE, 0)                                                       \
    /* p1 */                                                                   \
    G256_BAR();                                                                \
    G256_READ_B(bO, s01)                                                       \
    G256_READ_A(a0, s01, 0)                                                    \
    if (st1) { STG_B(sn1, T + 1, 1) }                                          \
    G256_MFMA(a1, bE, 1)                                                       \
    /* p2 */                                                                   \
    G256_BAR();                                                                \
    if (st1) { asm volatile("s_waitcnt vmcnt(4)" ::: "memory"); }              \
    else     { asm volatile("s_waitcnt vmcnt(0)" ::: "memory"); }              \
    G256_READ_A(a1, s01, 1)                                                    \
    if (st2) { STG_A(sn0, T + 2, 0) }                                          \
    G256_MFMA(a0, bO, 0)                                                       \
    /* p3 */                                                                   \
    G256_BAR();                                                                \
    if (st1) {                                                                 \
      G256_READ_B(bE, sx)                                                      \
      G256_READ_A(a0, sx, 0)                                                   \
    }                                                                          \
    if (st2) { STG_B(sn0, T + 2, 0) }                                          \
    G256_MFMA(a1, bO, 1)                                                       \
  }

// C[M,N] = A[M,K] * B[N,K]^T, bf16 in, fp32 acc, 256x256 tile, 512 threads.
// EPI: 0 = +bias -> bf16; 1 = +bias, gelu -> bf16
template<int EPI>
__global__ __launch_bounds__(512, 2) void gemm256(
    const __hip_bfloat16* __restrict__ A,   // [M,K]
    const __hip_bfloat16* __restrict__ B,   // [N,K]
    const float* __restrict__ bias,         // [N]
    __hip_bfloat16* __restrict__ outb,
    int M, int N, int K, int NT)
{
  __shared__ __align__(16) __hip_bfloat16 As[4][256 * 32];
  __shared__ __align__(16) __hip_bfloat16 Bs[4][256 * 32];
  const int tid  = threadIdx.x;
  const int lane = tid & 63;
  const int wave = tid >> 6;        // 0..7
  const int wr = wave >> 2;         // 0..1 (M half, 128 rows)
  const int wc = wave & 3;          // 0..3 (N quarter, 64 cols)
  const int fr = lane & 15;
  const int fq = lane >> 4;         // 0..3

  // bijective XCD swizzle (nwg % 8 == 0 for all call sites)
  const int nwg = gridDim.x;
  const int cpx = nwg >> 3;
  const int swz = (blockIdx.x & 7) * cpx + (blockIdx.x >> 3);
  const int mt = swz / NT, nt = swz % NT;
  const long bm = (long)mt * 256, bn = (long)nt * 256;

  // staging: thread t covers linear LDS 16B-chunk (i*512+t) of a k-half slot;
  // row = i*128 + (t>>2), phys chunk = t&3 -> logical chunk pre-swizzled.
  const int srow = tid >> 2;                       // 0..127
  const int sch  = (tid & 3) ^ ((tid >> 3) & 3);   // source k-chunk (involution)
  const __hip_bfloat16* Ag = A + (bm + srow) * (size_t)K + sch * 8;
  const __hip_bfloat16* Bg = B + (bn + srow) * (size_t)K + sch * 8;

  // ds_read bases (elements), swizzled chunk = fq ^ ((row>>1)&3) = fq ^ ((fr>>1)&3)
  const int swc = (fq ^ ((fr >> 1) & 3)) << 3;
  const int ard = (wr * 128 + fr) * 32 + swc;
  const int brd = (wc * 64 + fr) * 32 + swc;

  const floatx4 zero = {0.f, 0.f, 0.f, 0.f};
  floatx4 acc[8][4];
#pragma unroll
  for (int mi = 0; mi < 8; ++mi)
#pragma unroll
    for (int ni = 0; ni < 4; ++ni) acc[mi][ni] = zero;

  const int NKT = K >> 6;           // K-tiles of 64 (>=2 at all call sites)
  G256_KLOOP()

  // epilogue: C/D layout col = lane&15, row = (lane>>4)*4 + reg
#pragma unroll
  for (int mi = 0; mi < 8; ++mi) {
#pragma unroll
    for (int ni = 0; ni < 4; ++ni) {
      const long col = bn + wc * 64 + ni * 16 + fr;
      const float bv = bias[col];
#pragma unroll
      for (int r = 0; r < 4; ++r) {
        const long row = bm + wr * 128 + mi * 16 + fq * 4 + r;
        float v = acc[mi][ni][r] + bv;
        if (EPI == 1) {
          const float u = v + 0.044715f * v * v * v;
          v = v / (1.0f + __expf(-1.5957691216057308f * u));
        }
        outb[(size_t)row * N + col] = __float2bfloat16(v);
      }
    }
  }
}

// ---------------------------------------------------------------------------
// 256x256 8-phase split-K GEMM -> bf16 partials [SPLITS, M, N].
// ---------------------------------------------------------------------------
__global__ __launch_bounds__(512, 2) void gemm256_splitk(
    const __hip_bfloat16* __restrict__ A,   // [M,K]
    const __hip_bfloat16* __restrict__ B,   // [N,K]
    __hip_bfloat16* __restrict__ part,      // [SPLITS, M, N]
    int M, int N, int K, int Klen, int NT, int TPS)
{
  __shared__ __align__(16) __hip_bfloat16 As[4][256 * 32];
  __shared__ __align__(16) __hip_bfloat16 Bs[4][256 * 32];
  const int tid  = threadIdx.x;
  const int lane = tid & 63;
  const int wave = tid >> 6;
  const int wr = wave >> 2;
  const int wc = wave & 3;
  const int fr = lane & 15;
  const int fq = lane >> 4;

  const int nwg = gridDim.x;
  const int cpx = nwg >> 3;
  const int swz = (blockIdx.x & 7) * cpx + (blockIdx.x >> 3);
  const int zt = swz / TPS;
  const int tile = swz % TPS;
  const int mt = tile / NT, nt = tile % NT;
  const long bm = (long)mt * 256, bn = (long)nt * 256;
  const int kstart = zt * Klen;

  const int srow = tid >> 2;
  const int sch  = (tid & 3) ^ ((tid >> 3) & 3);
  const __hip_bfloat16* Ag = A + (bm + srow) * (size_t)K + kstart + sch * 8;
  const __hip_bfloat16* Bg = B + (bn + srow) * (size_t)K + kstart + sch * 8;

  const int swc = (fq ^ ((fr >> 1) & 3)) << 3;
  const int ard = (wr * 128 + fr) * 32 + swc;
  const int brd = (wc * 64 + fr) * 32 + swc;

  const floatx4 zero = {0.f, 0.f, 0.f, 0.f};
  floatx4 acc[8][4];
#pragma unroll
  for (int mi = 0; mi < 8; ++mi)
#pragma unroll
    for (int ni = 0; ni < 4; ++ni) acc[mi][ni] = zero;

  const int NKT = Klen >> 6;
  G256_KLOOP()

  __hip_bfloat16* outp = part + (size_t)zt * M * N;
#pragma unroll
  for (int mi = 0; mi < 8; ++mi) {
#pragma unroll
    for (int ni = 0; ni < 4; ++ni) {
      const long col = bn + wc * 64 + ni * 16 + fr;
#pragma unroll
      for (int r = 0; r < 4; ++r) {
        const long row = bm + wr * 128 + mi * 16 + fq * 4 + r;
        outp[(size_t)row * N + col] = __float2bfloat16(acc[mi][ni][r]);
      }
    }
  }
}

// ---------------------------------------------------------------------------
// 128x128 split-K GEMM (round 7 structure) -> bf16 partials. (attn-out proj)
// ---------------------------------------------------------------------------
#define GEMM_SWIZZLE()                                                        \
  const int flat = blockIdx.x + gridDim.x * (blockIdx.y + 32 * blockIdx.z);   \
  const int xcd_ = flat & 7;                                                  \
  int rsw_ = flat >> 3;                                                       \
  const int mt_ = xcd_ * 4 + (rsw_ & 3);                                      \
  rsw_ >>= 2;                                                                 \
  const int nt_ = rsw_ % gridDim.x;                                           \
  const int zt_ = rsw_ / gridDim.x;

#define GEMM_STAGE(buf, koff)                                      \
  async_copy16(Ag0 + (koff),           &Asl[buf][tid * 8]);        \
  async_copy16(Ag0 + (koff) + rstride, &Asl[buf][tid * 8 + 2048]); \
  async_copy16(Bg0 + (koff),           &Bsl[buf][tid * 8]);        \
  async_copy16(Bg0 + (koff) + rstride, &Bsl[buf][tid * 8 + 2048]);

#define GEMM_KLOOP(NI)                                                        \
  GEMM_STAGE(0, 0)                                                            \
  GEMM_STAGE(1, 32)                                                           \
  int cur = 0;                                                                \
  for (int it = 0; it < (NI); ++it) {                                         \
    if (it + 2 < (NI)) {                                                      \
      const int nb = (cur >= 1) ? cur - 1 : cur + 2;  /* (cur+2)%3 */         \
      GEMM_STAGE(nb, (it + 2) * 32)                                           \
      asm volatile("s_waitcnt vmcnt(8)" ::: "memory");                        \
    } else if (it + 1 < (NI)) {                                               \
      asm volatile("s_waitcnt vmcnt(4)" ::: "memory");                        \
    } else {                                                                  \
      asm volatile("s_waitcnt vmcnt(0)" ::: "memory");                        \
    }                                                                         \
    asm volatile("s_barrier" ::: "memory");                                   \
    const __hip_bfloat16* Ac = Asl[cur];                                      \
    const __hip_bfloat16* Bc = Bsl[cur];                                      \
    shortx8 afr[4], bfr[4];                                                   \
    _Pragma("unroll")                                                         \
    for (int i = 0; i < 4; ++i) {                                             \
      afr[i] = *(const shortx8*)&Ac[(wr * 64 + i * 16 + fr) * 32 + sw];       \
      bfr[i] = *(const shortx8*)&Bc[(wc * 64 + i * 16 + fr) * 32 + sw];       \
    }                                                                         \
    _Pragma("unroll")                                                         \
    for (int mi = 0; mi < 4; ++mi)                                            \
      _Pragma("unroll")                                                       \
      for (int ni = 0; ni < 4; ++ni)                                          \
        acc[mi][ni] = __builtin_amdgcn_mfma_f32_16x16x32_bf16(                \
            afr[mi], bfr[ni], acc[mi][ni], 0, 0, 0);                          \
    asm volatile("s_barrier" ::: "memory");                                   \
    cur = (cur == 2) ? 0 : cur + 1;                                           \
  }

__global__ __launch_bounds__(256) void gemm_bt_splitk(
    const __hip_bfloat16* __restrict__ A,   // [M,K]
    const __hip_bfloat16* __restrict__ B,   // [N,K]
    __hip_bfloat16* __restrict__ part,      // [splits, M, N] bf16
    int M, int N, int K, int Klen)
{
  __shared__ __align__(16) __hip_bfloat16 Asl[3][128 * 32];
  __shared__ __align__(16) __hip_bfloat16 Bsl[3][128 * 32];
  const int tid  = threadIdx.x;
  const int lane = tid & 63;
  const int wave = tid >> 6;
  const int wr = wave >> 1, wc = wave & 1;
  GEMM_SWIZZLE()
  const long bm = (long)mt_ * 128, bn = (long)nt_ * 128;
  const int kstart = zt_ * Klen;

  const int srow = tid >> 2;
  const int scol = ((((tid & 3) - (tid >> 3)) & 3) << 3);
  const __hip_bfloat16* Ag0 = A + (bm + srow) * (long)K + kstart + scol;
  const __hip_bfloat16* Bg0 = B + (bn + srow) * (long)K + kstart + scol;
  const long rstride = 64l * K;

  const int fr = lane & 15;
  const int fq = lane >> 4;
  const int sw = (((fq + ((fr >> 1) & 3)) & 3) << 3);

  const floatx4 zero = {0.f, 0.f, 0.f, 0.f};
  floatx4 acc[4][4];
#pragma unroll
  for (int mi = 0; mi < 4; ++mi)
#pragma unroll
    for (int ni = 0; ni < 4; ++ni) acc[mi][ni] = zero;

  const int NI = Klen >> 5;
  GEMM_KLOOP(NI)

  __hip_bfloat16* outp = part + (size_t)zt_ * M * N;
#pragma unroll
  for (int mi = 0; mi < 4; ++mi) {
#pragma unroll
    for (int ni = 0; ni < 4; ++ni) {
      const long col = bn + wc * 64 + ni * 16 + fr;
#pragma unroll
      for (int r = 0; r < 4; ++r) {
        const long row = bm + wr * 64 + mi * 16 + fq * 4 + r;
        outp[(size_t)row * N + col] = __float2bfloat16(acc[mi][ni][r]);
      }
    }
  }
}

// ---------------------------------------------------------------------------
// V transpose: qkv v-part [token, h*64+d] -> vt[(bh*64+d)*1024 + token]
// ---------------------------------------------------------------------------
__global__ __launch_bounds__(256) void transpose_v_kernel(
    const __hip_bfloat16* __restrict__ qkv, __hip_bfloat16* __restrict__ vt)
{
  const int bh = blockIdx.y;
  const int tt = blockIdx.x;
  const int b = bh >> 4, h = bh & 15;
  __shared__ __hip_bfloat16 tile[64][65];
  const int tid = threadIdx.x;
  const int r = tid >> 2;
  const int c = (tid & 3) << 4;
  const __hip_bfloat16* src = qkv + (size_t)(b * 1024 + tt * 64 + r) * 3072 + 2048 + h * 64 + c;
  U8 u0, u1;
  u0.v = *(const shortx8*)src;
  u1.v = *(const shortx8*)(src + 8);
#pragma unroll
  for (int j = 0; j < 8; ++j) { tile[r][c + j] = u0.h[j]; tile[r][c + 8 + j] = u1.h[j]; }
  __syncthreads();
  U8 w0, w1;
#pragma unroll
  for (int j = 0; j < 8; ++j) { w0.h[j] = tile[c + j][r]; w1.h[j] = tile[c + 8 + j][r]; }
  __hip_bfloat16* dst = vt + ((size_t)bh * 64 + r) * 1024 + tt * 64 + c;
  *(shortx8*)dst       = w0.v;
  *(shortx8*)(dst + 8) = w1.v;
}

// ---------------------------------------------------------------------------
// Banded-causal flash attention. One wave per (b,h,q-tile of 16).
// ---------------------------------------------------------------------------
__global__ __launch_bounds__(256) void attn_kernel(
    const __hip_bfloat16* __restrict__ qkv,
    const __hip_bfloat16* __restrict__ vt,
    __hip_bfloat16* __restrict__ ctx)
{
  const int wave = threadIdx.x >> 6;
  const int lane = threadIdx.x & 63;
  const int gw = blockIdx.x * 4 + wave;
  const int qt = gw & 63;
  const int bh = gw >> 6;
  const int b = bh >> 4, h = bh & 15;
  const int fr = lane & 15, fq = lane >> 4;
  const int q0 = qt << 4;

  __shared__ __align__(16) __hip_bfloat16 Plds[4][16 * 32];
  __hip_bfloat16* Pw = Plds[wave];

  const __hip_bfloat16* qrow = qkv + (size_t)(b * 1024 + q0 + fr) * 3072 + h * 64;
  const shortx8 aq0 = *(const shortx8*)(qrow + fq * 8);
  const shortx8 aq1 = *(const shortx8*)(qrow + 32 + fq * 8);

  const float SC = 0.125f * 1.44269504088896f;
  float m_r[4] = {-1e30f, -1e30f, -1e30f, -1e30f};
  float l_r[4] = {0.f, 0.f, 0.f, 0.f};
  const floatx4 zero = {0.f, 0.f, 0.f, 0.f};
  floatx4 o[4];
#pragma unroll
  for (int nd = 0; nd < 4; ++nd) o[nd] = zero;

  const int kt0 = (q0 >= 255) ? ((q0 - 255) >> 5) : 0;
  const int kt1 = (q0 + 15) >> 5;
  for (int kt = kt0; kt <= kt1; ++kt) {
    const int kbase = kt << 5;
    const __hip_bfloat16* krow0 = qkv + (size_t)(b * 1024 + kbase + fr) * 3072 + 1024 + h * 64;
    const __hip_bfloat16* krow1 = krow0 + 16 * 3072;
    const shortx8 bk00 = *(const shortx8*)(krow0 + fq * 8);
    const shortx8 bk01 = *(const shortx8*)(krow0 + 32 + fq * 8);
    const shortx8 bk10 = *(const shortx8*)(krow1 + fq * 8);
    const shortx8 bk11 = *(const shortx8*)(krow1 + 32 + fq * 8);
    floatx4 s0 = zero, s1 = zero;
    s0 = __builtin_amdgcn_mfma_f32_16x16x32_bf16(aq0, bk00, s0, 0, 0, 0);
    s0 = __builtin_amdgcn_mfma_f32_16x16x32_bf16(aq1, bk01, s0, 0, 0, 0);
    s1 = __builtin_amdgcn_mfma_f32_16x16x32_bf16(aq0, bk10, s1, 0, 0, 0);
    s1 = __builtin_amdgcn_mfma_f32_16x16x32_bf16(aq1, bk11, s1, 0, 0, 0);
#pragma unroll
    for (int r = 0; r < 4; ++r) { s0[r] *= SC; s1[r] *= SC; }
    if (kbase + 31 > q0 || kbase < q0 - 240) {
#pragma unroll
      for (int r = 0; r < 4; ++r) {
        const int tq = q0 + fq * 4 + r;
        const int j0 = kbase + fr;
        const int j1 = j0 + 16;
        if (j0 > tq || j0 < tq - 255) s0[r] = -3e38f;
        if (j1 > tq || j1 < tq - 255) s1[r] = -3e38f;
      }
    }
#pragma unroll
    for (int r = 0; r < 4; ++r) {
      float vmax = fmaxf(s0[r], s1[r]);
      vmax = fmaxf(vmax, __shfl_xor(vmax, 1));
      vmax = fmaxf(vmax, __shfl_xor(vmax, 2));
      vmax = fmaxf(vmax, __shfl_xor(vmax, 4));
      vmax = fmaxf(vmax, __shfl_xor(vmax, 8));
      const float mnew = fmaxf(m_r[r], vmax);
      const float alpha = exp2f(m_r[r] - mnew);
      const float p0 = exp2f(s0[r] - mnew);
      const float p1 = exp2f(s1[r] - mnew);
      m_r[r] = mnew;
      float ps = p0 + p1;
      ps += __shfl_xor(ps, 1);
      ps += __shfl_xor(ps, 2);
      ps += __shfl_xor(ps, 4);
      ps += __shfl_xor(ps, 8);
      l_r[r] = l_r[r] * alpha + ps;
      o[0][r] *= alpha; o[1][r] *= alpha; o[2][r] *= alpha; o[3][r] *= alpha;
      Pw[(fq * 4 + r) * 32 + fr]      = __float2bfloat16(p0);
      Pw[(fq * 4 + r) * 32 + 16 + fr] = __float2bfloat16(p1);
    }
    asm volatile("s_waitcnt lgkmcnt(0)" ::: "memory");
    const shortx8 ap = *(const shortx8*)&Pw[fr * 32 + fq * 8];
#pragma unroll
    for (int nd = 0; nd < 4; ++nd) {
      const shortx8 bv = *(const shortx8*)&vt[((size_t)bh * 64 + nd * 16 + fr) * 1024 + kbase + fq * 8];
      o[nd] = __builtin_amdgcn_mfma_f32_16x16x32_bf16(ap, bv, o[nd], 0, 0, 0);
    }
    asm volatile("s_waitcnt lgkmcnt(0)" ::: "memory");
  }
#pragma unroll
  for (int nd = 0; nd < 4; ++nd)
#pragma unroll
    for (int r = 0; r < 4; ++r)
      ctx[(size_t)(b * 1024 + q0 + fq * 4 + r) * 1024 + h * 64 + nd * 16 + fr] =
          __float2bfloat16(o[nd][r] / l_r[r]);
}

// ---------------------------------------------------------------------------
// Fused split-K reduce (bf16 partials) + bias + residual + LayerNorm.
// ---------------------------------------------------------------------------
template<int S, int WB>
__global__ __launch_bounds__(256) void ln_sum_kernel(
    const __hip_bfloat16* __restrict__ part,  // [S, 4096, 1024] bf16
    const float* __restrict__ resid,          // [4096, 1024]
    const float* __restrict__ bias,           // [1024]
    const float* __restrict__ g, const float* __restrict__ be,
    float* __restrict__ outf, __hip_bfloat16* __restrict__ outb)
{
  const int row = blockIdx.x;
  const int tid = threadIdx.x;
  const size_t base = (size_t)row * 1024;
  float4 v = ((const float4*)(resid + base))[tid];
  const float4 bv = ((const float4*)bias)[tid];
  v.x += bv.x; v.y += bv.y; v.z += bv.z; v.w += bv.w;
#pragma unroll
  for (int s = 0; s < S; ++s) {
    U4 p;
    p.v = *(const unsigned long long*)&part[(size_t)s * 4096 * 1024 + base + tid * 4];
    v.x += __bfloat162float(p.h[0]);
    v.y += __bfloat162float(p.h[1]);
    v.z += __bfloat162float(p.h[2]);
    v.w += __bfloat162float(p.h[3]);
  }
  float sm = v.x + v.y + v.z + v.w;
  float ss = v.x * v.x + v.y * v.y + v.z * v.z + v.w * v.w;
#pragma unroll
  for (int off = 1; off < 64; off <<= 1) {
    sm += __shfl_xor(sm, off);
    ss += __shfl_xor(ss, off);
  }
  __shared__ float red[8];
  if ((tid & 63) == 0) { red[tid >> 6] = sm; red[4 + (tid >> 6)] = ss; }
  __syncthreads();
  sm = red[0] + red[1] + red[2] + red[3];
  ss = red[4] + red[5] + red[6] + red[7];
  const float mu = sm * (1.0f / 1024.0f);
  const float rs = rsqrtf(ss * (1.0f / 1024.0f) - mu * mu + 1e-5f);
  const float4 gg = ((const float4*)g)[tid];
  const float4 bb = ((const float4*)be)[tid];
  float4 y;
  y.x = (v.x - mu) * rs * gg.x + bb.x;
  y.y = (v.y - mu) * rs * gg.y + bb.y;
  y.z = (v.z - mu) * rs * gg.z + bb.z;
  y.w = (v.w - mu) * rs * gg.w + bb.w;
  ((float4*)(outf + base))[tid] = y;
  if (WB) {
    bf4 o4;
    o4.h[0] = __float2bfloat16(y.x);
    o4.h[1] = __float2bfloat16(y.y);
    o4.h[2] = __float2bfloat16(y.z);
    o4.h[3] = __float2bfloat16(y.w);
    *(bf4*)(outb + base + tid * 4) = o4;
  }
}

// ---------------------------------------------------------------------------
extern "C" void kernel_launch(void* const* d_in, const int* in_sizes, int n_in,
                              void* d_out, int out_size, void* d_ws, size_t ws_size,
                              hipStream_t stream) {
  const float* x    = (const float*)d_in[0];
  const float* Wqkv = (const float*)d_in[1];
  const float* bqkv = (const float*)d_in[2];
  const float* Wo   = (const float*)d_in[3];
  const float* bo   = (const float*)d_in[4];
  const float* W1   = (const float*)d_in[5];
  const float* b1   = (const float*)d_in[6];
  const float* W2   = (const float*)d_in[7];
  const float* b2   = (const float*)d_in[8];
  const float* g1   = (const float*)d_in[9];
  const float* be1  = (const float*)d_in[10];
  const float* g2   = (const float*)d_in[11];
  const float* be2  = (const float*)d_in[12];

  char* ws = (char*)d_ws;
  size_t off = 0;
  auto alloc = [&](size_t bytes) -> void* {
    void* p = ws + off;
    off += (bytes + 255) & ~(size_t)255;
    return p;
  };
  __hip_bfloat16* wqkvb = (__hip_bfloat16*)alloc(6291456);
  __hip_bfloat16* wob   = (__hip_bfloat16*)alloc(2097152);
  __hip_bfloat16* w1b   = (__hip_bfloat16*)alloc(8388608);
  __hip_bfloat16* w2b   = (__hip_bfloat16*)alloc(8388608);
  __hip_bfloat16* xb    = (__hip_bfloat16*)alloc(8388608);
  __hip_bfloat16* qkvb  = (__hip_bfloat16*)alloc(25165824);
  __hip_bfloat16* vtb   = (__hip_bfloat16*)alloc(8388608);
  __hip_bfloat16* ctxb  = (__hip_bfloat16*)alloc(8388608);
  __hip_bfloat16* part  = (__hip_bfloat16*)alloc(4u * 8388608);
  float*          x1f   = (float*)alloc(16777216);
  __hip_bfloat16* x1b   = (__hip_bfloat16*)alloc(8388608);
  __hip_bfloat16* hb    = (__hip_bfloat16*)alloc(33554432);
  (void)ws_size; (void)in_sizes; (void)n_in; (void)out_size;

  // 0. single-launch cast of x + all weights to bf16
  cast_all_kernel<<<16384, 256, 0, stream>>>(x, xb, 4096,
                                             Wqkv, wqkvb, 3072,
                                             Wo, wob, 1024,
                                             W1, w1b, 4096,
                                             W2, w2b);
  // 1. QKV projection (256x256 8-phase, 192 wgs)
  gemm256<0><<<192, 512, 0, stream>>>(xb, wqkvb, bqkv, qkvb, 4096, 3072, 1024, 12);
  // 2. attention
  transpose_v_kernel<<<dim3(16, 64), 256, 0, stream>>>(qkvb, vtb);
  attn_kernel<<<1024, 256, 0, stream>>>(qkvb, vtb, ctxb);
  // 3. output projection (split-K=2) + fused reduce+resid+LN1
  gemm_bt_splitk<<<dim3(8, 32, 2), 256, 0, stream>>>(ctxb, wob, part, 4096, 1024, 1024, 512);
  ln_sum_kernel<2, 1><<<4096, 256, 0, stream>>>(part, x, bo, g1, be1, x1f, x1b);
  // 4. FFN (FFN1: 256x256 8-phase, 256 wgs = 1/CU)
  gemm256<1><<<256, 512, 0, stream>>>(x1b, w1b, b1, hb, 4096, 4096, 1024, 16);
  // FFN2: 256x256 8-phase split-K=4 (64 tiles x 4 splits = 256 wgs)
  gemm256_splitk<<<256, 512, 0, stream>>>(hb, w2b, part, 4096, 1024, 4096, 1024, 4, 64);
  ln_sum_kernel<4, 0><<<4096, 256, 0, stream>>>(part, x1f, b2, g2, be2, (float*)d_out, nullptr);
}